// Round 1
// 110.737 us; speedup vs baseline: 1.0775x; 1.0775x over previous
//
#include <hip/hip_runtime.h>

// FlowNetC correlation on MI355X (round 8): MFMA banded-correlation.
// out[b, dyi*21+dxi, y, x] = (1/128) * sum_c in1[b,c,y,x] * in2[b,c,y+dy,x+dx]
//   dy = 2*(dyi-10), dx = 2*(dxi-10); in2 zero outside [0,96)^2.
//
// Parity split x = 2*xi + p  =>  out[xi, dxi] = sum_c A[xi,c] * B[xi+dxi-10, c]
// = width-21 band of A·B^T per (b, y, dy, p). Tiled 16x16x32 bf16 MFMA.
//
// R8 vs R7 (119.3 us): two read-path changes.
//  (1) NT stores for the 65 MB output (write-once). Per XCD, ~8 MB of
//      streaming stores were sweeping the 4 MiB L2 and evicting the A/B
//      panels (per-(b,half) working set = 1.2+2.2 MB) that the 21x dy-reuse
//      depends on. `nt` keeps them resident.
//  (2) Block restructure: 3 waves share one (b,y); wave w handles
//      dyi = 3*g + w (7 groups cover 0..20 exactly, no idle waves). The A
//      block (24.6 KB) is staged once into LDS and fragments come from
//      ds_read_b128; only B is loaded from global per wave. A L2 traffic /3,
//      per-wave VMEM issue /2. Epilogue reuses the same LDS after a barrier
//      (block LDS 33.6 -> 25.2 KB).
// Epilogue scatter/store logic unchanged from R7 (swapped-operand MFMA so the
// LDS scatter is 4-way-max on banks; coalesced b128 read-back).

#define BB 4
#define CC_ALL 128
#define HH 96
#define WW 96
#define ND 21

typedef __attribute__((ext_vector_type(8))) short short8;
typedef __attribute__((ext_vector_type(4))) float floatx4;

__device__ __forceinline__ ushort f2bf(float f) {
    unsigned u = __builtin_bit_cast(unsigned, f);
    return (ushort)((u + 0x7FFFu + ((u >> 16) & 1u)) >> 16);
}

// ---- pre-pass (fused): f32 [b][c][y][x] -> bf16 [b][y][p][kq(16)][xi(48)][8c]
// blockIdx.y selects tensor (0: in1, scaled by 1/128; 1: in2).
__global__ __launch_bounds__(256)
void transpose_cvt2(const float* __restrict__ in1, const float* __restrict__ in2,
                    ushort* __restrict__ T1, ushort* __restrict__ T2) {
    const int sel = blockIdx.y;
    const float* __restrict__ src = sel ? in2 : in1;
    ushort* __restrict__ dst = sel ? T2 : T1;
    const float mul = sel ? 1.0f : (1.0f / 128.0f);

    int g  = blockIdx.x * 256 + threadIdx.x;   // < 4*96*16*24 = 147456
    int t  = g % 24;
    int t1 = g / 24;
    int kq = t1 % 16;
    int t2 = t1 / 16;
    int y  = t2 % 96;
    int b  = t2 / 96;

    const float* s = src + (((b * CC_ALL + kq * 8) * HH + y) * WW) + 4 * t;
    ushort e0[8], e1[8], o0[8], o1[8];      // xi = 2t and 2t+1
#pragma unroll
    for (int j = 0; j < 8; ++j) {
        float4 f = *(const float4*)(s + j * (HH * WW));
        e0[j] = f2bf(f.x * mul);
        o0[j] = f2bf(f.y * mul);
        e1[j] = f2bf(f.z * mul);
        o1[j] = f2bf(f.w * mul);
    }
    int base = (((b * 96 + y) * 2 + 0) * 16 + kq) * 48 + 2 * t;
    uint4 w;
    ushort* d0 = dst + base * 8;                 // parity 0
    w.x = e0[0] | ((unsigned)e0[1] << 16); w.y = e0[2] | ((unsigned)e0[3] << 16);
    w.z = e0[4] | ((unsigned)e0[5] << 16); w.w = e0[6] | ((unsigned)e0[7] << 16);
    *(uint4*)(d0) = w;
    w.x = e1[0] | ((unsigned)e1[1] << 16); w.y = e1[2] | ((unsigned)e1[3] << 16);
    w.z = e1[4] | ((unsigned)e1[5] << 16); w.w = e1[6] | ((unsigned)e1[7] << 16);
    *(uint4*)(d0 + 8) = w;
    ushort* d1 = d0 + 16 * 48 * 8;               // parity 1 (+6144 ushorts)
    w.x = o0[0] | ((unsigned)o0[1] << 16); w.y = o0[2] | ((unsigned)o0[3] << 16);
    w.z = o0[4] | ((unsigned)o0[5] << 16); w.w = o0[6] | ((unsigned)o0[7] << 16);
    *(uint4*)(d1) = w;
    w.x = o1[0] | ((unsigned)o1[1] << 16); w.y = o1[2] | ((unsigned)o1[3] << 16);
    w.z = o1[4] | ((unsigned)o1[5] << 16); w.w = o1[6] | ((unsigned)o1[7] << 16);
    *(uint4*)(d1 + 8) = w;
}

// ---------------- main: banded MFMA correlation ------------------------------
// Grid 2688, XCD-aware decode: k = n%8 -> (b = k>>1, half = k&1);
// j = n>>3 in [0,336) -> (y = half*48 + j%48, g = j/48 in [0,7)).
// Block = 3 waves sharing (b,y): wave w computes dyi = 3*g + w.
// A(b,y) staged once into LDS; B per wave from global (L2-resident, nt-free).
// Scale 1/128 pre-folded into T1. MFMA operand order: (bf, af) — see header.
__global__ __launch_bounds__(192)
void corr_mfma(const ushort* __restrict__ T1, const ushort* __restrict__ T2,
               float* __restrict__ out) {
    // Union: [0, 24576 B) = staged A block; after compute barrier, the same
    // storage is 3 per-wave epilogue tiles [21 d][96 x (+4 pad)] floats.
    __shared__ __align__(16) float lds[3 * ND * 100];   // 25200 B

    const int n_   = blockIdx.x;
    const int k    = n_ & 7;
    const int j    = n_ >> 3;             // [0, 336)
    const int b    = k >> 1;
    const int half = k & 1;
    const int y    = half * 48 + (j % 48);
    const int g    = j / 48;              // dyi group [0,7)

    const int tid  = threadIdx.x;
    const int w    = tid >> 6;            // wave id = dyi offset in group
    const int lane = tid & 63;
    const int nn   = lane & 15;           // col index of D = in1-x tile-local
    const int q    = lane >> 4;           // quad; D row m = q*4 + r = in2-x local
    const int dyi  = g * 3 + w;           // 0..20, each exactly once per (b,y)
    const int dy   = 2 * (dyi - 10);
    const int Y2   = y + dy;
    const bool rowok = (unsigned)Y2 < (unsigned)HH;

    // ---- stage A(b,y): 2 parities x 6144 ushorts = 24576 B = 1536 float4 ----
    {
        const float4* __restrict__ srcA =
            (const float4*)(T1 + ((b * 96 + y) * 2) * 6144);
        float4* dstA = (float4*)lds;
#pragma unroll
        for (int i = 0; i < 8; ++i)
            dstA[tid + i * 192] = srcA[tid + i * 192];
    }
    __syncthreads();

    // 7 (t = in1 M-tile, s = in2 N-tile) band pairs per parity
    const int TS_t[7] = {0, 0, 1, 1, 1, 2, 2};
    const int TS_s[7] = {0, 1, 0, 1, 2, 1, 2};

    floatx4 acc[14];
#pragma unroll
    for (int i = 0; i < 14; ++i) acc[i] = (floatx4){0.f, 0.f, 0.f, 0.f};

    if (rowok) {
        const ushort* Alds = (const ushort*)lds;
        const ushort* B0 = T2 + ((b * 96 + Y2) * 2) * 6144;
#pragma unroll
        for (int ch = 0; ch < 4; ++ch) {          // K chunks of 32 channels
            const int kofs = (4 * ch + q) * 384 + nn * 8;  // (kq)*48*8 + xi*8
#pragma unroll
            for (int p = 0; p < 2; ++p) {
                const ushort* Ab = Alds + p * 6144 + kofs;   // LDS (ds_read_b128)
                const ushort* Bb = B0 + p * 6144 + kofs;     // global (L2)
                short8 af0 = *(const short8*)(Ab);
                short8 af1 = *(const short8*)(Ab + 128);   // +16 xi
                short8 af2 = *(const short8*)(Ab + 256);   // +32 xi
                short8 bf0 = *(const short8*)(Bb);
                short8 bf1 = *(const short8*)(Bb + 128);
                short8 bf2 = *(const short8*)(Bb + 256);
                // operand order (bf, af): D rows = in2-x, cols = in1-x
                acc[p*7+0] = __builtin_amdgcn_mfma_f32_16x16x32_bf16(bf0, af0, acc[p*7+0], 0, 0, 0);
                acc[p*7+1] = __builtin_amdgcn_mfma_f32_16x16x32_bf16(bf1, af0, acc[p*7+1], 0, 0, 0);
                acc[p*7+2] = __builtin_amdgcn_mfma_f32_16x16x32_bf16(bf0, af1, acc[p*7+2], 0, 0, 0);
                acc[p*7+3] = __builtin_amdgcn_mfma_f32_16x16x32_bf16(bf1, af1, acc[p*7+3], 0, 0, 0);
                acc[p*7+4] = __builtin_amdgcn_mfma_f32_16x16x32_bf16(bf2, af1, acc[p*7+4], 0, 0, 0);
                acc[p*7+5] = __builtin_amdgcn_mfma_f32_16x16x32_bf16(bf1, af2, acc[p*7+5], 0, 0, 0);
                acc[p*7+6] = __builtin_amdgcn_mfma_f32_16x16x32_bf16(bf2, af2, acc[p*7+6], 0, 0, 0);
            }
        }
    }
    // all waves must be done reading the A-LDS image before epilogue overwrite
    __syncthreads();

    // ---- epilogue: C-tiles -> per-wave LDS [d][x] -> coalesced nt stores ----
    float* wl = lds + w * (ND * 100);
    {
        floatx4 z = {0.f, 0.f, 0.f, 0.f};
        for (int kk = lane; kk < (ND * 100) / 4; kk += 64) ((floatx4*)wl)[kk] = z;
    }
    if (rowok) {
#pragma unroll
        for (int p = 0; p < 2; ++p) {
#pragma unroll
            for (int i = 0; i < 7; ++i) {
                const int t = TS_t[i], s = TS_s[i];
#pragma unroll
                for (int r = 0; r < 4; ++r) {
                    // D[m][nn]: row m = q*4+r (in2-local), col = nn (in1-local)
                    int m = q * 4 + r;
                    int d = 16 * s + m - 16 * t - nn + 10;   // dxi
                    int x = 2 * (16 * t + nn) + p;
                    if (0 <= d && d <= 20)
                        wl[d * 100 + x] = acc[p * 7 + i][r];
                }
            }
        }
    }
    // same-wave LDS RAW: compiler inserts lgkmcnt waits; no barrier needed.
    const int base0 = ((b * (ND * ND) + dyi * ND) * HH + y) * WW;
#pragma unroll
    for (int i = 0; i < 8; ++i) {
        int fl = i * 64 + lane;               // float4 index, 21*24 = 504 total
        if (fl < 504) {
            int d  = fl / 24;
            int xi = fl % 24;
            floatx4 v = *(const floatx4*)(wl + d * 100 + xi * 4);
            // write-once output: nt keeps the A/B panels resident in L2
            __builtin_nontemporal_store(v, (floatx4*)(out + base0 + d * (HH * WW) + xi * 4));
        }
    }
}

// ---------------- fallback (R3 VALU kernel) if ws too small ------------------
#define TY 8
#define CCH 4
#define NCHUNK (CC_ALL / CCH)
#define GX 4
#define NTHR 192
#define L1P 52
#define L1U (2 * L1P)
#define W2P 68
#define L2U (2 * W2P)

__global__ __launch_bounds__(NTHR, 2)
void corr_kernel(const float* __restrict__ in1,
                 const float* __restrict__ in2,
                 float* __restrict__ out) {
    __shared__ float lds1[CCH * TY * L1U];
    __shared__ float lds2[CCH * TY * L2U];
    const int tid = threadIdx.x;
    const int y0  = blockIdx.x * TY;
    const int dyi = blockIdx.y;
    const int b   = blockIdx.z;
    const int dy  = 2 * (dyi - 10);
    const int r   = tid / 24;
    const int un_ = tid % 24;
    const int p   = un_ / 12;
    const int u0  = (un_ % 12) * GX;
    float acc[ND * GX];
#pragma unroll
    for (int i = 0; i < ND * GX; ++i) acc[i] = 0.f;
    const float* in1b = in1 + b * (CC_ALL * HH * WW);
    const float* in2b = in2 + b * (CC_ALL * HH * WW);
    {
        float4 z = make_float4(0.f, 0.f, 0.f, 0.f);
        for (int k = tid; k < (CCH * TY * L2U) / 4; k += NTHR)
            ((float4*)lds2)[k] = z;
    }
    for (int ch = 0; ch < NCHUNK; ++ch) {
        const int c0 = ch * CCH;
        __syncthreads();
#pragma unroll
        for (int k = 0; k < 4; ++k) {
            int f  = tid + k * NTHR;
            int x4 = f % 24;
            int rc = f / 24;
            int c  = rc >> 3, rr = rc & 7;
            const float4 g = *(const float4*)&in1b[(c0 + c) * (HH * WW) + (y0 + rr) * WW + x4 * 4];
            float* base = &lds1[(c * TY + rr) * L1U];
            *(float2*)&base[      2 * x4] = make_float2(g.x, g.z);
            *(float2*)&base[L1P + 2 * x4] = make_float2(g.y, g.w);
        }
#pragma unroll
        for (int k = 0; k < 4; ++k) {
            int f  = tid + k * NTHR;
            int x4 = f % 24;
            int rc = f / 24;
            int c  = rc >> 3, rr = rc & 7;
            int Y  = y0 + rr + dy;
            if ((unsigned)Y < HH) {
                const float4 g = *(const float4*)&in2b[(c0 + c) * (HH * WW) + Y * WW + x4 * 4];
                float* base = &lds2[(c * TY + rr) * L2U];
                *(float2*)&base[      2 * x4 + 10] = make_float2(g.x, g.z);
                *(float2*)&base[W2P + 2 * x4 + 10] = make_float2(g.y, g.w);
            }
        }
        __syncthreads();
#pragma unroll
        for (int c = 0; c < CCH; ++c) {
            const float* a4  = &lds1[(c * TY + r) * L1U + p * L1P + u0];
            const float* v24 = &lds2[(c * TY + r) * L2U + p * W2P + u0];
            float4 af = *(const float4*)a4;
            float v[24];
#pragma unroll
            for (int m = 0; m < 24; m += 4) {
                float4 t = *(const float4*)&v24[m];
                v[m] = t.x; v[m + 1] = t.y; v[m + 2] = t.z; v[m + 3] = t.w;
            }
#pragma unroll
            for (int id = 0; id < ND; ++id) {
                acc[id * GX + 0] += af.x * v[id + 0];
                acc[id * GX + 1] += af.y * v[id + 1];
                acc[id * GX + 2] += af.z * v[id + 2];
                acc[id * GX + 3] += af.w * v[id + 3];
            }
        }
    }
    const float scale = 1.0f / 128.0f;
#pragma unroll
    for (int id = 0; id < ND; ++id) {
        int d = dyi * ND + id;
        int base = ((b * (ND * ND) + d) * HH + (y0 + r)) * WW;
#pragma unroll
        for (int jj = 0; jj < GX; ++jj) {
            int x = 2 * (u0 + jj) + p;
            out[base + x] = acc[id * GX + jj] * scale;
        }
    }
}

extern "C" void kernel_launch(void* const* d_in, const int* in_sizes, int n_in,
                              void* d_out, int out_size, void* d_ws, size_t ws_size,
                              hipStream_t stream) {
    const float* in1 = (const float*)d_in[0];
    const float* in2 = (const float*)d_in[1];
    float* out = (float*)d_out;
    const size_t elems = (size_t)BB * CC_ALL * HH * WW;      // 4,718,592 per tensor
    const size_t need  = 2 * elems * sizeof(ushort);         // 18,874,368 B

    if (ws_size >= need) {
        ushort* T1 = (ushort*)d_ws;
        ushort* T2 = T1 + elems;
        dim3 tg(147456 / 256, 2);   // 576 blocks x {in1, in2}
        hipLaunchKernelGGL(transpose_cvt2, tg, dim3(256), 0, stream, in1, in2, T1, T2);
        // 2688 = 8 XCD groups x (48 y x 7 dyi-groups); 192 thr = 3 waves
        hipLaunchKernelGGL(corr_mfma, dim3(2688), dim3(192), 0, stream, T1, T2, out);
    } else {
        dim3 grid(HH / TY, ND, BB);
        hipLaunchKernelGGL(corr_kernel, grid, dim3(NTHR), 0, stream, in1, in2, out);
    }
}